// Round 1
// baseline (175.615 us; speedup 1.0000x reference)
//
#include <hip/hip_runtime.h>

// DeLaN sin-net fused kernel for MI355X (gfx950).
//
// Algebraic restructuring: jac einsum + first layers of m/c nets collapse into
// four 30x30 matrices (A,B from c_w1*W2*W1; P,Q from m_w1*W2), precomputed per
// launch in a tiny kernel into d_ws. Main kernel: 1 thread = 1 batch element,
// weights in LDS (wave-uniform broadcast reads), ~5.3k FMA/elem.

#define NT 256

// ---- packed weight layout in d_ws / LDS (floats), rows padded for b128 ----
constexpr int OFF_AT   = 0;     // [h][32], h<30, j<30 : c-net from cos(pre_ld)
constexpr int OFF_BT   = 960;   // [h][32]             : c-net from cos(pre_lo)
constexpr int OFF_PT   = 1920;  // [h][32]             : m-net from sin(pre_ld)
constexpr int OFF_QT   = 2880;  // [h][32]             : m-net from sin(pre_lo)
constexpr int OFF_W1LD = 3840;  // [h][8], d<7  : ld_w1
constexpr int OFF_W1LO = 4080;  // [h][8]       : lo_w1
constexpr int OFF_W1G  = 4320;  // [h][8]       : g_w1
constexpr int OFF_G2T  = 4560;  // [h][8], k<7  : g_w2^T
constexpr int OFF_M2T  = 4800;  // [j][8], k<7  : m_w2^T
constexpr int OFF_C2T  = 5040;  // [j][8], k<7  : c_w2^T
constexpr int OFF_MQT  = 5280;  // [d][32], d<7 : m_w1[:,28+d] (qDDot part)
constexpr int OFF_CQT  = 5504;  // [d][32], d<7 : c_w1[:,196+d] (qDot part)
constexpr int OFF_BLD  = 5728;  // 30 : ld_b1
constexpr int OFF_BLO  = 5758;  // 30 : lo_b1
constexpr int OFF_BG   = 5788;  // 30 : g_b1
constexpr int OFF_BM   = 5818;  // 30 : m_b1 + m_w1[:, :28] @ [ld_b2;lo_b2]
constexpr int OFF_BC   = 5848;  // 30 : c_b1
constexpr int OFF_BOUT = 5878;  // 7  : m_b2 + c_b2 + g_b2
constexpr int WS_N     = 5888;  // 23.5 KB

__global__ void precompute_kernel(
    const float* __restrict__ ld_w1, const float* __restrict__ ld_b1,
    const float* __restrict__ ld_w2, const float* __restrict__ ld_b2,
    const float* __restrict__ lo_w1, const float* __restrict__ lo_b1,
    const float* __restrict__ lo_w2, const float* __restrict__ lo_b2,
    const float* __restrict__ g_w1,  const float* __restrict__ g_b1,
    const float* __restrict__ g_w2,  const float* __restrict__ g_b2,
    const float* __restrict__ m_w1,  const float* __restrict__ m_b1,
    const float* __restrict__ m_w2,  const float* __restrict__ m_b2,
    const float* __restrict__ c_w1,  const float* __restrict__ c_b1,
    const float* __restrict__ c_w2,  const float* __restrict__ c_b2,
    float* __restrict__ ws)
{
    int i = blockIdx.x * blockDim.x + threadIdx.x;
    if (i < 900) {                       // AT[h][j] = sum_{o<7,d} c_w1[j,o*7+d]*ld_w2[o,h]*ld_w1[h,d]
        int h = i / 30, j = i % 30;
        float acc = 0.f;
        for (int o = 0; o < 7; ++o) {
            float t = 0.f;
            for (int d = 0; d < 7; ++d) t += c_w1[j*203 + o*7 + d] * ld_w1[h*7 + d];
            acc += ld_w2[o*30 + h] * t;
        }
        ws[OFF_AT + h*32 + j] = acc;
    } else if (i < 1800) {               // BT[h][j] = sum_{o<21,d} c_w1[j,(7+o)*7+d]*lo_w2[o,h]*lo_w1[h,d]
        int e = i - 900, h = e / 30, j = e % 30;
        float acc = 0.f;
        for (int o = 0; o < 21; ++o) {
            float t = 0.f;
            for (int d = 0; d < 7; ++d) t += c_w1[j*203 + (7+o)*7 + d] * lo_w1[h*7 + d];
            acc += lo_w2[o*30 + h] * t;
        }
        ws[OFF_BT + h*32 + j] = acc;
    } else if (i < 2700) {               // PT[h][j] = sum_{o<7} m_w1[j,o]*ld_w2[o,h]
        int e = i - 1800, h = e / 30, j = e % 30;
        float acc = 0.f;
        for (int o = 0; o < 7; ++o) acc += m_w1[j*35 + o] * ld_w2[o*30 + h];
        ws[OFF_PT + h*32 + j] = acc;
    } else if (i < 3600) {               // QT[h][j] = sum_{o<21} m_w1[j,7+o]*lo_w2[o,h]
        int e = i - 2700, h = e / 30, j = e % 30;
        float acc = 0.f;
        for (int o = 0; o < 21; ++o) acc += m_w1[j*35 + 7 + o] * lo_w2[o*30 + h];
        ws[OFF_QT + h*32 + j] = acc;
    } else if (i < 3810) { int e = i - 3600; ws[OFF_W1LD + (e/7)*8 + e%7] = ld_w1[e]; }
    else if (i < 4020) { int e = i - 3810; ws[OFF_W1LO + (e/7)*8 + e%7] = lo_w1[e]; }
    else if (i < 4230) { int e = i - 4020; ws[OFF_W1G  + (e/7)*8 + e%7] = g_w1[e]; }
    else if (i < 4440) { int e = i - 4230; int h = e/7, k = e%7; ws[OFF_G2T + h*8 + k] = g_w2[k*30 + h]; }
    else if (i < 4650) { int e = i - 4440; int j = e/7, k = e%7; ws[OFF_M2T + j*8 + k] = m_w2[k*30 + j]; }
    else if (i < 4860) { int e = i - 4650; int j = e/7, k = e%7; ws[OFF_C2T + j*8 + k] = c_w2[k*30 + j]; }
    else if (i < 5070) { int e = i - 4860; int d = e/30, j = e%30; ws[OFF_MQT + d*32 + j] = m_w1[j*35 + 28 + d]; }
    else if (i < 5280) { int e = i - 5070; int d = e/30, j = e%30; ws[OFF_CQT + d*32 + j] = c_w1[j*203 + 196 + d]; }
    else if (i < 5310) { int j = i - 5280; ws[OFF_BLD + j] = ld_b1[j]; }
    else if (i < 5340) { int j = i - 5310; ws[OFF_BLO + j] = lo_b1[j]; }
    else if (i < 5370) { int j = i - 5340; ws[OFF_BG + j] = g_b1[j]; }
    else if (i < 5400) {                 // BM[j] = m_b1[j] + sum_o m_w1[j,o]*ld_b2[o] + sum_o m_w1[j,7+o]*lo_b2[o]
        int j = i - 5370;
        float acc = m_b1[j];
        for (int o = 0; o < 7;  ++o) acc += m_w1[j*35 + o]     * ld_b2[o];
        for (int o = 0; o < 21; ++o) acc += m_w1[j*35 + 7 + o] * lo_b2[o];
        ws[OFF_BM + j] = acc;
    }
    else if (i < 5430) { int j = i - 5400; ws[OFF_BC + j] = c_b1[j]; }
    else if (i < 5437) { int k = i - 5430; ws[OFF_BOUT + k] = m_b2[k] + c_b2[k] + g_b2[k]; }
}

__global__ __launch_bounds__(NT) void delan_main(
    const float* __restrict__ x, const float* __restrict__ ws, float* __restrict__ out)
{
    __shared__ float w[WS_N];
    __shared__ float xs[NT * 21];
    const int t = threadIdx.x;
    const long long b0 = (long long)blockIdx.x * NT;

    for (int i = t; i < WS_N; i += NT) w[i] = ws[i];
    {
        const float* xb = x + b0 * 21;
        for (int i = t; i < NT * 21; i += NT) xs[i] = xb[i];
    }
    __syncthreads();

    const float* xt = &xs[t * 21];
    float q[7];
#pragma unroll
    for (int d = 0; d < 7; ++d) q[d] = xt[d];

    float acc_o[7];
#pragma unroll
    for (int k = 0; k < 7; ++k) acc_o[k] = w[OFF_BOUT + k];

    // ---- g net: out += sin(q@g_w1^T + g_b1) @ g_w2^T ----
#pragma unroll 2
    for (int h = 0; h < 30; ++h) {
        float pre = w[OFF_BG + h];
#pragma unroll
        for (int d = 0; d < 7; ++d) pre += q[d] * w[OFF_W1G + h*8 + d];
        float s = __sinf(pre);
#pragma unroll
        for (int k = 0; k < 7; ++k) acc_o[k] += s * w[OFF_G2T + h*8 + k];
    }

    // ---- m/c hidden pre-activations via collapsed 30x30 matrices ----
    float mz[30], cz[30];
#pragma unroll
    for (int j = 0; j < 30; ++j) { mz[j] = w[OFF_BM + j]; cz[j] = w[OFF_BC + j]; }

#pragma unroll 1
    for (int d = 0; d < 7; ++d) {
        float qd  = xt[7 + d];
        float qdd = xt[14 + d];
#pragma unroll
        for (int j = 0; j < 30; ++j) {
            mz[j] += qdd * w[OFF_MQT + d*32 + j];
            cz[j] += qd  * w[OFF_CQT + d*32 + j];
        }
    }

#pragma unroll 1
    for (int h = 0; h < 30; ++h) {           // ld path
        float pre = w[OFF_BLD + h];
#pragma unroll
        for (int d = 0; d < 7; ++d) pre += q[d] * w[OFF_W1LD + h*8 + d];
        float s = __sinf(pre), c = __cosf(pre);
#pragma unroll
        for (int j = 0; j < 30; ++j) {
            mz[j] += s * w[OFF_PT + h*32 + j];
            cz[j] += c * w[OFF_AT + h*32 + j];
        }
    }

#pragma unroll 1
    for (int h = 0; h < 30; ++h) {           // lo path
        float pre = w[OFF_BLO + h];
#pragma unroll
        for (int d = 0; d < 7; ++d) pre += q[d] * w[OFF_W1LO + h*8 + d];
        float s = __sinf(pre), c = __cosf(pre);
#pragma unroll
        for (int j = 0; j < 30; ++j) {
            mz[j] += s * w[OFF_QT + h*32 + j];
            cz[j] += c * w[OFF_BT + h*32 + j];
        }
    }

    // ---- sigmoid + second layers of m/c nets ----
#pragma unroll
    for (int j = 0; j < 30; ++j) {
        float em = __expf(-mz[j]);
        float sm = __builtin_amdgcn_rcpf(1.f + em);
        float ec = __expf(-cz[j]);
        float sc = __builtin_amdgcn_rcpf(1.f + ec);
#pragma unroll
        for (int k = 0; k < 7; ++k)
            acc_o[k] += sm * w[OFF_M2T + j*8 + k] + sc * w[OFF_C2T + j*8 + k];
    }

    __syncthreads();
#pragma unroll
    for (int k = 0; k < 7; ++k) xs[t*7 + k] = acc_o[k];
    __syncthreads();
    {
        float* ob = out + b0 * 7;
        for (int i = t; i < NT * 7; i += NT) ob[i] = xs[i];
    }
}

extern "C" void kernel_launch(void* const* d_in, const int* in_sizes, int n_in,
                              void* d_out, int out_size, void* d_ws, size_t ws_size,
                              hipStream_t stream)
{
    const float* x = (const float*)d_in[0];
    float* ws = (float*)d_ws;

    precompute_kernel<<<(5437 + 255) / 256, 256, 0, stream>>>(
        (const float*)d_in[1],  (const float*)d_in[2],
        (const float*)d_in[3],  (const float*)d_in[4],
        (const float*)d_in[5],  (const float*)d_in[6],
        (const float*)d_in[7],  (const float*)d_in[8],
        (const float*)d_in[9],  (const float*)d_in[10],
        (const float*)d_in[11], (const float*)d_in[12],
        (const float*)d_in[13], (const float*)d_in[14],
        (const float*)d_in[15], (const float*)d_in[16],
        (const float*)d_in[17], (const float*)d_in[18],
        (const float*)d_in[19], (const float*)d_in[20],
        ws);

    const int batch = out_size / 7;            // 262144
    const int nblk  = batch / NT;              // 1024
    delan_main<<<nblk, NT, 0, stream>>>(x, ws, (float*)d_out);
}

// Round 2
// 168.478 us; speedup vs baseline: 1.0424x; 1.0424x over previous
//
#include <hip/hip_runtime.h>

// DeLaN sin-net fused kernel for MI355X (gfx950).
//
// R1: weights read straight from global `ws` with uniform indices -> scalar
// s_load path (SMEM pipe), freeing the LDS pipe which was the R0 bottleneck
// (~1200 broadcast ds_read_b128/thread ~= 75us). LDS now only stages x/out.

#define NT 256

// ---- packed weight layout in d_ws (floats), rows padded to 32/8 ----
constexpr int OFF_AT   = 0;     // [h][32], h<30, j<30 : c-net from cos(pre_ld)
constexpr int OFF_BT   = 960;   // [h][32]             : c-net from cos(pre_lo)
constexpr int OFF_PT   = 1920;  // [h][32]             : m-net from sin(pre_ld)
constexpr int OFF_QT   = 2880;  // [h][32]             : m-net from sin(pre_lo)
constexpr int OFF_W1LD = 3840;  // [h][8], d<7  : ld_w1
constexpr int OFF_W1LO = 4080;  // [h][8]       : lo_w1
constexpr int OFF_W1G  = 4320;  // [h][8]       : g_w1
constexpr int OFF_G2T  = 4560;  // [h][8], k<7  : g_w2^T
constexpr int OFF_M2T  = 4800;  // [j][8], k<7  : m_w2^T
constexpr int OFF_C2T  = 5040;  // [j][8], k<7  : c_w2^T
constexpr int OFF_MQT  = 5280;  // [d][32], d<7 : m_w1[:,28+d] (qDDot part)
constexpr int OFF_CQT  = 5504;  // [d][32], d<7 : c_w1[:,196+d] (qDot part)
constexpr int OFF_BLD  = 5728;  // 30 : ld_b1
constexpr int OFF_BLO  = 5758;  // 30 : lo_b1
constexpr int OFF_BG   = 5788;  // 30 : g_b1
constexpr int OFF_BM   = 5818;  // 30 : m_b1 + m_w1[:, :28] @ [ld_b2;lo_b2]
constexpr int OFF_BC   = 5848;  // 30 : c_b1
constexpr int OFF_BOUT = 5878;  // 7  : m_b2 + c_b2 + g_b2
constexpr int WS_N     = 5888;  // 23.5 KB

__global__ void precompute_kernel(
    const float* __restrict__ ld_w1, const float* __restrict__ ld_b1,
    const float* __restrict__ ld_w2, const float* __restrict__ ld_b2,
    const float* __restrict__ lo_w1, const float* __restrict__ lo_b1,
    const float* __restrict__ lo_w2, const float* __restrict__ lo_b2,
    const float* __restrict__ g_w1,  const float* __restrict__ g_b1,
    const float* __restrict__ g_w2,  const float* __restrict__ g_b2,
    const float* __restrict__ m_w1,  const float* __restrict__ m_b1,
    const float* __restrict__ m_w2,  const float* __restrict__ m_b2,
    const float* __restrict__ c_w1,  const float* __restrict__ c_b1,
    const float* __restrict__ c_w2,  const float* __restrict__ c_b2,
    float* __restrict__ ws)
{
    int i = blockIdx.x * blockDim.x + threadIdx.x;
    if (i < 900) {                       // AT[h][j] = sum_{o<7,d} c_w1[j,o*7+d]*ld_w2[o,h]*ld_w1[h,d]
        int h = i / 30, j = i % 30;
        float acc = 0.f;
#pragma unroll
        for (int o = 0; o < 7; ++o) {
            float t = 0.f;
#pragma unroll
            for (int d = 0; d < 7; ++d) t += c_w1[j*203 + o*7 + d] * ld_w1[h*7 + d];
            acc += ld_w2[o*30 + h] * t;
        }
        ws[OFF_AT + h*32 + j] = acc;
    } else if (i < 1800) {               // BT[h][j] = sum_{o<21,d} c_w1[j,(7+o)*7+d]*lo_w2[o,h]*lo_w1[h,d]
        int e = i - 900, h = e / 30, j = e % 30;
        float acc = 0.f;
#pragma unroll
        for (int o = 0; o < 21; ++o) {
            float t = 0.f;
#pragma unroll
            for (int d = 0; d < 7; ++d) t += c_w1[j*203 + (7+o)*7 + d] * lo_w1[h*7 + d];
            acc += lo_w2[o*30 + h] * t;
        }
        ws[OFF_BT + h*32 + j] = acc;
    } else if (i < 2700) {               // PT[h][j] = sum_{o<7} m_w1[j,o]*ld_w2[o,h]
        int e = i - 1800, h = e / 30, j = e % 30;
        float acc = 0.f;
#pragma unroll
        for (int o = 0; o < 7; ++o) acc += m_w1[j*35 + o] * ld_w2[o*30 + h];
        ws[OFF_PT + h*32 + j] = acc;
    } else if (i < 3600) {               // QT[h][j] = sum_{o<21} m_w1[j,7+o]*lo_w2[o,h]
        int e = i - 2700, h = e / 30, j = e % 30;
        float acc = 0.f;
#pragma unroll
        for (int o = 0; o < 21; ++o) acc += m_w1[j*35 + 7 + o] * lo_w2[o*30 + h];
        ws[OFF_QT + h*32 + j] = acc;
    } else if (i < 3810) { int e = i - 3600; ws[OFF_W1LD + (e/7)*8 + e%7] = ld_w1[e]; }
    else if (i < 4020) { int e = i - 3810; ws[OFF_W1LO + (e/7)*8 + e%7] = lo_w1[e]; }
    else if (i < 4230) { int e = i - 4020; ws[OFF_W1G  + (e/7)*8 + e%7] = g_w1[e]; }
    else if (i < 4440) { int e = i - 4230; int h = e/7, k = e%7; ws[OFF_G2T + h*8 + k] = g_w2[k*30 + h]; }
    else if (i < 4650) { int e = i - 4440; int j = e/7, k = e%7; ws[OFF_M2T + j*8 + k] = m_w2[k*30 + j]; }
    else if (i < 4860) { int e = i - 4650; int j = e/7, k = e%7; ws[OFF_C2T + j*8 + k] = c_w2[k*30 + j]; }
    else if (i < 5070) { int e = i - 4860; int d = e/30, j = e%30; ws[OFF_MQT + d*32 + j] = m_w1[j*35 + 28 + d]; }
    else if (i < 5280) { int e = i - 5070; int d = e/30, j = e%30; ws[OFF_CQT + d*32 + j] = c_w1[j*203 + 196 + d]; }
    else if (i < 5310) { int j = i - 5280; ws[OFF_BLD + j] = ld_b1[j]; }
    else if (i < 5340) { int j = i - 5310; ws[OFF_BLO + j] = lo_b1[j]; }
    else if (i < 5370) { int j = i - 5340; ws[OFF_BG + j] = g_b1[j]; }
    else if (i < 5400) {                 // BM[j] = m_b1[j] + m_w1[j,:28] @ [ld_b2;lo_b2]
        int j = i - 5370;
        float acc = m_b1[j];
#pragma unroll
        for (int o = 0; o < 7;  ++o) acc += m_w1[j*35 + o]     * ld_b2[o];
#pragma unroll
        for (int o = 0; o < 21; ++o) acc += m_w1[j*35 + 7 + o] * lo_b2[o];
        ws[OFF_BM + j] = acc;
    }
    else if (i < 5430) { int j = i - 5400; ws[OFF_BC + j] = c_b1[j]; }
    else if (i < 5437) { int k = i - 5430; ws[OFF_BOUT + k] = m_b2[k] + c_b2[k] + g_b2[k]; }
}

__global__ __launch_bounds__(NT) void delan_main(
    const float* __restrict__ x, const float* __restrict__ ws, float* __restrict__ out)
{
    __shared__ float xs[NT * 21];
    const int t = threadIdx.x;
    const long long b0 = (long long)blockIdx.x * NT;

    // coalesced float4 stage of x into LDS
    {
        const float4* xb = (const float4*)(x + b0 * 21);
        float4* xs4 = (float4*)xs;
        for (int i = t; i < NT * 21 / 4; i += NT) xs4[i] = xb[i];
    }
    __syncthreads();

    const float* xt = &xs[t * 21];
    float q[7];
#pragma unroll
    for (int d = 0; d < 7; ++d) q[d] = xt[d];

    float acc_o[7];
#pragma unroll
    for (int k = 0; k < 7; ++k) acc_o[k] = ws[OFF_BOUT + k];

    // ---- g net: out += sin(q@g_w1^T + g_b1) @ g_w2^T ----
#pragma unroll 2
    for (int h = 0; h < 30; ++h) {
        float pre = ws[OFF_BG + h];
#pragma unroll
        for (int d = 0; d < 7; ++d) pre += q[d] * ws[OFF_W1G + h*8 + d];
        float s = __sinf(pre);
#pragma unroll
        for (int k = 0; k < 7; ++k) acc_o[k] += s * ws[OFF_G2T + h*8 + k];
    }

    // ---- m/c hidden pre-activations via collapsed 30x30 matrices ----
    float mz[30], cz[30];
#pragma unroll
    for (int j = 0; j < 30; ++j) { mz[j] = ws[OFF_BM + j]; cz[j] = ws[OFF_BC + j]; }

#pragma unroll 1
    for (int d = 0; d < 7; ++d) {
        float qd  = xt[7 + d];
        float qdd = xt[14 + d];
#pragma unroll
        for (int j = 0; j < 30; ++j) {
            mz[j] += qdd * ws[OFF_MQT + d*32 + j];
            cz[j] += qd  * ws[OFF_CQT + d*32 + j];
        }
    }

#pragma unroll 2
    for (int h = 0; h < 30; ++h) {           // ld path
        float pre = ws[OFF_BLD + h];
#pragma unroll
        for (int d = 0; d < 7; ++d) pre += q[d] * ws[OFF_W1LD + h*8 + d];
        float s = __sinf(pre), c = __cosf(pre);
#pragma unroll
        for (int j = 0; j < 30; ++j) {
            mz[j] += s * ws[OFF_PT + h*32 + j];
            cz[j] += c * ws[OFF_AT + h*32 + j];
        }
    }

#pragma unroll 2
    for (int h = 0; h < 30; ++h) {           // lo path
        float pre = ws[OFF_BLO + h];
#pragma unroll
        for (int d = 0; d < 7; ++d) pre += q[d] * ws[OFF_W1LO + h*8 + d];
        float s = __sinf(pre), c = __cosf(pre);
#pragma unroll
        for (int j = 0; j < 30; ++j) {
            mz[j] += s * ws[OFF_QT + h*32 + j];
            cz[j] += c * ws[OFF_BT + h*32 + j];
        }
    }

    // ---- sigmoid + second layers of m/c nets ----
#pragma unroll 2
    for (int j = 0; j < 30; ++j) {
        float em = __expf(-mz[j]);
        float sm = __builtin_amdgcn_rcpf(1.f + em);
        float ec = __expf(-cz[j]);
        float sc = __builtin_amdgcn_rcpf(1.f + ec);
#pragma unroll
        for (int k = 0; k < 7; ++k)
            acc_o[k] += sm * ws[OFF_M2T + j*8 + k] + sc * ws[OFF_C2T + j*8 + k];
    }

    __syncthreads();
#pragma unroll
    for (int k = 0; k < 7; ++k) xs[t*7 + k] = acc_o[k];
    __syncthreads();
    {
        const float4* xs4 = (const float4*)xs;
        float4* ob = (float4*)(out + b0 * 7);
        for (int i = t; i < NT * 7 / 4; i += NT) ob[i] = xs4[i];
    }
}

extern "C" void kernel_launch(void* const* d_in, const int* in_sizes, int n_in,
                              void* d_out, int out_size, void* d_ws, size_t ws_size,
                              hipStream_t stream)
{
    const float* x = (const float*)d_in[0];
    float* ws = (float*)d_ws;

    precompute_kernel<<<(5437 + 255) / 256, 256, 0, stream>>>(
        (const float*)d_in[1],  (const float*)d_in[2],
        (const float*)d_in[3],  (const float*)d_in[4],
        (const float*)d_in[5],  (const float*)d_in[6],
        (const float*)d_in[7],  (const float*)d_in[8],
        (const float*)d_in[9],  (const float*)d_in[10],
        (const float*)d_in[11], (const float*)d_in[12],
        (const float*)d_in[13], (const float*)d_in[14],
        (const float*)d_in[15], (const float*)d_in[16],
        (const float*)d_in[17], (const float*)d_in[18],
        (const float*)d_in[19], (const float*)d_in[20],
        ws);

    const int batch = out_size / 7;            // 262144
    const int nblk  = batch / NT;              // 1024
    delan_main<<<nblk, NT, 0, stream>>>(x, ws, (float*)d_out);
}